// Round 18
// baseline (188.156 us; speedup 1.0000x reference)
//
#include <hip/hip_runtime.h>
#include <math.h>
#include <utility>

#define BATCH 16384
#define INPUT_DIM 512
#define HIDDEN 1024
#define NROT 32
#define NANG 496   // 32*31/2

typedef _Float16 half8 __attribute__((ext_vector_type(8)));
typedef _Float16 half4 __attribute__((ext_vector_type(4)));
typedef float    f32x4 __attribute__((ext_vector_type(4)));

// ---------------------------------------------------------------------------
// f32 -> f16 conversion (prep pass), 8 elems/thread
// ---------------------------------------------------------------------------
__global__ __launch_bounds__(256) void cvt_f32_f16(
    const float* __restrict__ src, _Float16* __restrict__ dst, int n8)
{
    const int i = blockIdx.x * 256 + threadIdx.x;
    if (i < n8) {
        const float4* s = (const float4*)src + (size_t)i * 2;
        const float4 a = s[0], b = s[1];
        half8 h;
        h[0]=(_Float16)a.x; h[1]=(_Float16)a.y; h[2]=(_Float16)a.z; h[3]=(_Float16)a.w;
        h[4]=(_Float16)b.x; h[5]=(_Float16)b.y; h[6]=(_Float16)b.z; h[7]=(_Float16)b.w;
        *(half8*)(dst + (size_t)i * 8) = h;
    }
}

// ---------------------------------------------------------------------------
// Single-pass f16 MFMA GEMM (NT): C = epi(A[M,K] @ B[N,K]^T + bias)
//   EPI=0: relu -> f16 Ch[M][Nout]
//   EPI=1: theta -> f32 Cf[M][Nout]
// (unchanged from round 15)
// ---------------------------------------------------------------------------
template<int EPI>
__global__ __launch_bounds__(256) void gemm_nt_f16(
    const _Float16* __restrict__ A, const _Float16* __restrict__ B,
    const float* __restrict__ bias, float* __restrict__ Cf,
    _Float16* __restrict__ Ch, int M, int N, int K, int Nout)
{
    constexpr int BK = 32;
    __shared__ _Float16 sA[2][128 * BK];
    __shared__ _Float16 sB[2][128 * BK];

    const int tid = threadIdx.x;
    const int m0 = blockIdx.y * 128;
    const int n0 = blockIdx.x * 128;

    const int rA  = tid >> 2;
    const int k8  = tid & 3;
    const int swW = ((k8 ^ (rA & 3)) << 3);

    half8 rg[4];

    auto load_tile = [&](int kt) {
        const size_t koff = (size_t)kt * BK + k8 * 8;
        rg[0] = *(const half8*)(A + (size_t)(m0 + rA) * K + koff);
        rg[1] = *(const half8*)(A + (size_t)(m0 + rA + 64) * K + koff);
        half8 z;
        #pragma unroll
        for (int j = 0; j < 8; ++j) z[j] = (_Float16)0.f;
        if (EPI == 0 || (n0 + rA) < N)
            rg[2] = *(const half8*)(B + (size_t)(n0 + rA) * K + koff);
        else rg[2] = z;
        if (EPI == 0 || (n0 + rA + 64) < N)
            rg[3] = *(const half8*)(B + (size_t)(n0 + rA + 64) * K + koff);
        else rg[3] = z;
    };

    auto write_tile = [&](int buf) {
        *(half8*)&sA[buf][ rA       * BK + swW] = rg[0];
        *(half8*)&sA[buf][(rA + 64) * BK + swW] = rg[1];
        *(half8*)&sB[buf][ rA       * BK + swW] = rg[2];
        *(half8*)&sB[buf][(rA + 64) * BK + swW] = rg[3];
    };

    const int lane = tid & 63;
    const int wid  = tid >> 6;
    const int wr = wid >> 1, wc = wid & 1;
    const int fr = lane & 15, fq = lane >> 4;
    const int swR   = ((fq ^ (fr & 3)) << 3);
    const int aBase = (wr * 64 + fr) * BK + swR;
    const int bBase = (wc * 64 + fr) * BK + swR;

    f32x4 acc[4][4];
    #pragma unroll
    for (int i = 0; i < 4; ++i)
        #pragma unroll
        for (int j = 0; j < 4; ++j) acc[i][j] = (f32x4)(0.f);

    const int NT = K / BK;
    load_tile(0);
    write_tile(0);
    int cur = 0;

    for (int kt = 0; kt < NT; ++kt) {
        const bool more = (kt + 1 < NT);
        if (more) load_tile(kt + 1);
        __syncthreads();

        half8 a_[4], b_[4];
        #pragma unroll
        for (int f = 0; f < 4; ++f) {
            a_[f] = *(const half8*)&sA[cur][aBase + f * 16 * BK];
            b_[f] = *(const half8*)&sB[cur][bBase + f * 16 * BK];
        }
        #pragma unroll
        for (int fm = 0; fm < 4; ++fm)
            #pragma unroll
            for (int fn = 0; fn < 4; ++fn)
                acc[fm][fn] = __builtin_amdgcn_mfma_f32_16x16x32_f16(
                    a_[fm], b_[fn], acc[fm][fn], 0, 0, 0);

        if (more) write_tile(cur ^ 1);
        cur ^= 1;
    }

    if (EPI == 0) {
        #pragma unroll
        for (int fn = 0; fn < 4; ++fn) {
            const int col = n0 + wc * 64 + fn * 16 + fr;
            const float bv = bias[col];
            #pragma unroll
            for (int fm = 0; fm < 4; ++fm) {
                const int row0 = m0 + wr * 64 + fm * 16 + fq * 4;
                #pragma unroll
                for (int r = 0; r < 4; ++r)
                    Ch[(size_t)(row0 + r) * Nout + col] =
                        (_Float16)fmaxf(acc[fm][fn][r] + bv, 0.f);
            }
        }
    } else {
        #pragma unroll
        for (int fn = 0; fn < 4; ++fn) {
            const int col = n0 + wc * 64 + fn * 16 + fr;
            if (col < Nout) {
                const float bv = bias[col];
                #pragma unroll
                for (int fm = 0; fm < 4; ++fm) {
                    const int row0 = m0 + wr * 64 + fm * 16 + fq * 4;
                    #pragma unroll
                    for (int r = 0; r < 4; ++r)
                        Cf[(size_t)(row0 + r) * Nout + col] = acc[fm][fn][r] + bv;
                }
            }
        }
    }
}

// ---------------------------------------------------------------------------
// Rotate — 8 chunks of 62 rotations + 3-level MFMA tree (f32 cs, R15 rules).
//   R17 lesson: chain is VALU-bound (f16 cs cvt regressed); the lever is
//   serial chain length. 8 waves/block, 2 batches; wave w = chunk w for both
//   batches (half-wave each). Chain VALU per thread halves vs R15 (62 rot).
//   NT-mfma: mfma(a,b) = A @ B^T, both operands row-fragments; all product
//   stores are column-major (lane's 4 D rows at fixed col -> half4), i.e.
//   store(X) leaves X^T readable as rows. Verified R15 recipes reused:
//    L1 p even: mfma(C_{2p+1}^T, C_{2p}) = P_p^T  -> store -> P_p rows
//    L1 p odd : mfma(C_{2p}, C_{2p+1}^T) = P_p    -> store -> P_p^T rows
//    L2 q0: mfma(P1^T, P0) = Q0^T -> store -> Q0 rows
//    L2 q1: mfma(P2, P3^T) = Q1   -> store -> Q1^T rows
//    L3   : mfma(Q1^T, Q0) = R^T -> b128 f32 stores (R15 final formula)
//   LDS 40KB: cs f32 [0,2048) (dead after chains -> L1 products PROD f16
//   [0,8192) w/ read->bar->write; factors FACT f16 [4096..20480) 16x1024
//   (slots 0-3 overlaid by PROD after their L1 reads); Q f16 [8192,12288)
//   overlays factor slots 4-7; R f32 [0,2048) overlays PROD after L2 reads.
//   4 blocks/CU = 32 waves/CU (vs ~12 at R15's 24KB/256thr).
// ---------------------------------------------------------------------------
struct IJTbl { unsigned char i[NANG]; unsigned char j[NANG]; };
constexpr IJTbl make_ij_tbl() {
    IJTbl t{};
    int k = 0;
    for (int i = 0; i < NROT - 1; ++i)
        for (int j = i + 1; j < NROT; ++j) { t.i[k] = (unsigned char)i; t.j[k] = (unsigned char)j; ++k; }
    return t;
}
constexpr IJTbl IJT = make_ij_tbl();

#define FACT_H 4096    // f16 idx: 16 factor slots x 1024 -> [4096, 20480)
#define PROD_H 0       // f16 idx: 8 L1-product slots x 1024 -> [0, 8192)
#define QH     8192    // f16 idx: 4 L2-product slots x 1024 -> [8192, 12288)
#define RF32   0       // f32 idx: R output, 2 x 1024 f32 -> [0, 2048)

template<int M>   // forward: rotations 2M then 2M+1 (row rule)
__device__ __forceinline__ void rot_fwd(const f32x4 q, float (&v)[NROT]) {
    {
        constexpr int k = 2 * M;
        constexpr int i = IJT.i[k], j = IJT.j[k];
        const float vi = v[i], vj = v[j];
        v[i] = fmaf(q[0], vi,  q[1] * vj);
        v[j] = fmaf(q[0], vj, -q[1] * vi);
    }
    {
        constexpr int k = 2 * M + 1;
        constexpr int i = IJT.i[k], j = IJT.j[k];
        const float vi = v[i], vj = v[j];
        v[i] = fmaf(q[2], vi,  q[3] * vj);
        v[j] = fmaf(q[2], vj, -q[3] * vi);
    }
}

template<int M>   // reverse: rotations 2M+1 then 2M (column rule)
__device__ __forceinline__ void rot_rev(const f32x4 q, float (&v)[NROT]) {
    {
        constexpr int k = 2 * M + 1;
        constexpr int i = IJT.i[k], j = IJT.j[k];
        const float vi = v[i], vj = v[j];
        v[i] = fmaf(q[2], vi, -q[3] * vj);
        v[j] = fmaf(q[2], vj,  q[3] * vi);
    }
    {
        constexpr int k = 2 * M;
        constexpr int i = IJT.i[k], j = IJT.j[k];
        const float vi = v[i], vj = v[j];
        v[i] = fmaf(q[0], vi, -q[1] * vj);
        v[j] = fmaf(q[0], vj,  q[1] * vi);
    }
}

template<int W, int T>   // chunk W covers f32x4 groups M in [31W, 31W+31)
__device__ __forceinline__ void chain_step(const float* __restrict__ lcs,
                                           float (&v)[NROT]) {
    if constexpr ((W & 1) == 0) {
        constexpr int M = 31 * W + T;                 // forward order
        const f32x4 q = *(const f32x4*)(lcs + M * 4);
        rot_fwd<M>(q, v);
    } else {
        constexpr int M = 31 * W + (30 - T);          // reverse order
        const f32x4 q = *(const f32x4*)(lcs + M * 4);
        rot_rev<M>(q, v);
    }
}

template<int W, size_t... Ts>
__device__ __forceinline__ void chain_runW(const float* __restrict__ lcs,
                                           float (&v)[NROT],
                                           std::index_sequence<Ts...>) {
    (chain_step<W, (int)Ts>(lcs, v), ...);
}

template<int W>
__device__ __forceinline__ void chain_and_store(const float* __restrict__ lcs,
                                                _Float16* __restrict__ lh,
                                                int ba, int r) {
    float v[NROT];
    #pragma unroll
    for (int c = 0; c < NROT; ++c) v[c] = (c == r) ? 1.f : 0.f;
    chain_runW<W>(lcs, v, std::make_index_sequence<31>{});   // 31 x 2 = 62 rot

    // even W: row r of C_W; odd W: row r of C_W^T — same vectorized store.
    const int base = FACT_H + (ba * 8 + W) * 1024;
    #pragma unroll
    for (int kq = 0; kq < 4; ++kq) {
        half8 hv;
        #pragma unroll
        for (int j = 0; j < 8; ++j) hv[j] = (_Float16)v[kq * 8 + j];
        *(half8*)&lh[base + r * 32 + ((kq ^ (r & 3)) << 3)] = hv;
    }
}

__global__ __launch_bounds__(512) void rotate_kernel(
    const float* __restrict__ theta, float* __restrict__ out)
{
    __shared__ float smem[10240];  // 40 KB
    _Float16* lh = (_Float16*)smem;

    const int tid  = threadIdx.x;
    const int wid  = tid >> 6;             // 0..7
    const int lane = tid & 63;
    const int hw   = (tid >> 5) & 1;       // half-wave = batch for chains
    const int r    = tid & 31;
    const int fr = lane & 15, fq = lane >> 4;
    const size_t b0 = (size_t)blockIdx.x * 2;

    // ---- stage: theta -> sincos -> (c,s) f32 pairs (as R15) ----
    if (tid < 248) {
        const f32x4 th = *(const f32x4*)(theta + b0 * NANG + tid * 4);
        f32x4 p0, p1;
        float s, c;
        __sincosf(th[0], &s, &c); p0[0] = c; p0[1] = s;
        __sincosf(th[1], &s, &c); p0[2] = c; p0[3] = s;
        __sincosf(th[2], &s, &c); p1[0] = c; p1[1] = s;
        __sincosf(th[3], &s, &c); p1[2] = c; p1[3] = s;
        *(f32x4*)&smem[tid * 8]     = p0;
        *(f32x4*)&smem[tid * 8 + 4] = p1;
    }
    __syncthreads();

    // ---- chunk chains: wave w -> chunk w, half-wave -> batch ----
    const float* lcs = smem + hw * 992;
    switch (wid) {
        case 0: chain_and_store<0>(lcs, lh, hw, r); break;
        case 1: chain_and_store<1>(lcs, lh, hw, r); break;
        case 2: chain_and_store<2>(lcs, lh, hw, r); break;
        case 3: chain_and_store<3>(lcs, lh, hw, r); break;
        case 4: chain_and_store<4>(lcs, lh, hw, r); break;
        case 5: chain_and_store<5>(lcs, lh, hw, r); break;
        case 6: chain_and_store<6>(lcs, lh, hw, r); break;
        default: chain_and_store<7>(lcs, lh, hw, r); break;
    }
    __syncthreads();

    // ---- L1: 8 waves -> (ba = wid>>2, p = wid&3): P_p = C_{2p} * C_{2p+1}
    {
        const int ba = wid >> 2, p = wid & 3;
        const int Eb = FACT_H + (ba * 8 + 2 * p)     * 1024;  // C_{2p} rows
        const int Ob = FACT_H + (ba * 8 + 2 * p + 1) * 1024;  // C_{2p+1}^T rows
        const int Asrc = ((p & 1) == 0) ? Ob : Eb;
        const int Bsrc = ((p & 1) == 0) ? Eb : Ob;
        const int swz = (fq ^ (fr & 3)) << 3;
        half8 a[2], b[2];
        #pragma unroll
        for (int mi = 0; mi < 2; ++mi) {
            a[mi] = *(const half8*)&lh[Asrc + (mi * 16 + fr) * 32 + swz];
            b[mi] = *(const half8*)&lh[Bsrc + (mi * 16 + fr) * 32 + swz];
        }
        __syncthreads();   // all factor reads done before PROD overlays slots 0-3
        const int Pb = PROD_H + (ba * 4 + p) * 1024;
        #pragma unroll
        for (int mi = 0; mi < 2; ++mi)
            #pragma unroll
            for (int ni = 0; ni < 2; ++ni) {
                const f32x4 d = __builtin_amdgcn_mfma_f32_16x16x32_f16(
                    a[mi], b[ni], (f32x4)(0.f), 0, 0, 0);
                half4 hv;
                #pragma unroll
                for (int q = 0; q < 4; ++q) hv[q] = (_Float16)d[q];
                const int col  = ni * 16 + fr;
                const int rowb = (mi * 16 + fq * 4) ^ ((col & 3) << 3);
                *(half4*)&lh[Pb + col * 32 + rowb] = hv;
            }
    }
    __syncthreads();

    // ---- L2: waves 0-3 -> (ba = wid>>1, q = wid&1)
    //  q0: mfma(P1^T, P0) = Q0^T -> store -> Q0 rows
    //  q1: mfma(P2, P3^T) = Q1   -> store -> Q1^T rows
    if (wid < 4) {
        const int ba = wid >> 1, qi = wid & 1;
        const int Asrc = PROD_H + (ba * 4 + (qi == 0 ? 1 : 2)) * 1024;
        const int Bsrc = PROD_H + (ba * 4 + (qi == 0 ? 0 : 3)) * 1024;
        const int swz = (fq ^ (fr & 3)) << 3;
        half8 a[2], b[2];
        #pragma unroll
        for (int mi = 0; mi < 2; ++mi) {
            a[mi] = *(const half8*)&lh[Asrc + (mi * 16 + fr) * 32 + swz];
            b[mi] = *(const half8*)&lh[Bsrc + (mi * 16 + fr) * 32 + swz];
        }
        const int Qb = QH + (ba * 2 + qi) * 1024;
        #pragma unroll
        for (int mi = 0; mi < 2; ++mi)
            #pragma unroll
            for (int ni = 0; ni < 2; ++ni) {
                const f32x4 d = __builtin_amdgcn_mfma_f32_16x16x32_f16(
                    a[mi], b[ni], (f32x4)(0.f), 0, 0, 0);
                half4 hv;
                #pragma unroll
                for (int q = 0; q < 4; ++q) hv[q] = (_Float16)d[q];
                const int col  = ni * 16 + fr;
                const int rowb = (mi * 16 + fq * 4) ^ ((col & 3) << 3);
                *(half4*)&lh[Qb + col * 32 + rowb] = hv;
            }
    }
    __syncthreads();

    // ---- L3: waves 0-1 -> ba = wid: mfma(Q1^T, Q0) = R^T; lane = 4
    //      consecutive cols of R at fixed row -> b128 stores (R15 formula).
    if (wid < 2) {
        const int ba = wid;
        const int Ab = QH + (ba * 2 + 1) * 1024;   // Q1^T rows
        const int Bb = QH + (ba * 2 + 0) * 1024;   // Q0 rows
        const int swz = (fq ^ (fr & 3)) << 3;
        #pragma unroll
        for (int mi = 0; mi < 2; ++mi) {
            const half8 a = *(const half8*)&lh[Ab + (mi * 16 + fr) * 32 + swz];
            #pragma unroll
            for (int ni = 0; ni < 2; ++ni) {
                const half8 b = *(const half8*)&lh[Bb + (ni * 16 + fr) * 32 + swz];
                const f32x4 d = __builtin_amdgcn_mfma_f32_16x16x32_f16(
                    a, b, (f32x4)(0.f), 0, 0, 0);
                const int row  = ni * 16 + fr;            // row of R
                const int colq = mi * 4 + fq;             // col block (4 f32)
                *(f32x4*)&smem[RF32 + ba * 1024 + row * 32 + ((colq ^ (row & 7)) << 2)] = d;
            }
        }
    }
    __syncthreads();

    // ---- coalesced copy-out (512 threads, 512 float4s) ----
    {
        const int idx = tid;                 // 0..511
        const int ba  = idx >> 8;
        const int f4i = idx & 255;
        const int row = f4i >> 3;
        const int cc  = f4i & 7;
        const f32x4 val =
            *(const f32x4*)&smem[RF32 + ba * 1024 + row * 32 + ((cc ^ (row & 7)) << 2)];
        *(f32x4*)(out + (b0 + ba) * 1024 + (size_t)f4i * 4) = val;
    }
}

// ---------------------------------------------------------------------------
extern "C" void kernel_launch(void* const* d_in, const int* in_sizes, int n_in,
                              void* d_out, int out_size, void* d_ws, size_t ws_size,
                              hipStream_t stream)
{
    const float* x  = (const float*)d_in[0];   // [16384, 512]
    const float* W1 = (const float*)d_in[1];   // [1024, 512]
    const float* b1 = (const float*)d_in[2];   // [1024]
    const float* W2 = (const float*)d_in[3];   // [496, 1024]
    const float* b2 = (const float*)d_in[4];   // [496]
    float* out = (float*)d_out;                // [16384, 32, 32]

    // d_out (67.1 MB) doubles as f16 scratch; rotate rewrites all of it last.
    _Float16* h16  = (_Float16*)d_out;               // 33.55 MB
    _Float16* x16  = h16  + (size_t)BATCH * HIDDEN;  // 16.78 MB
    _Float16* W116 = x16  + (size_t)BATCH * INPUT_DIM;
    _Float16* W216 = W116 + (size_t)HIDDEN * INPUT_DIM;
    float*    th   = (float*)d_ws;                   // theta [16384][496] f32

    cvt_f32_f16<<<dim3((BATCH * INPUT_DIM / 8 + 255) / 256), 256, 0, stream>>>(
        x, x16, BATCH * INPUT_DIM / 8);
    cvt_f32_f16<<<dim3((HIDDEN * INPUT_DIM / 8 + 255) / 256), 256, 0, stream>>>(
        W1, W116, HIDDEN * INPUT_DIM / 8);
    cvt_f32_f16<<<dim3((NANG * HIDDEN / 8 + 255) / 256), 256, 0, stream>>>(
        W2, W216, NANG * HIDDEN / 8);

    gemm_nt_f16<0><<<dim3(HIDDEN / 128, BATCH / 128), 256, 0, stream>>>(
        x16, W116, b1, nullptr, h16, BATCH, HIDDEN, INPUT_DIM, HIDDEN);

    gemm_nt_f16<1><<<dim3((NANG + 127) / 128, BATCH / 128), 256, 0, stream>>>(
        h16, W216, b2, th, nullptr, BATCH, NANG, HIDDEN, NANG);

    rotate_kernel<<<dim3(BATCH / 2), 512, 0, stream>>>(th, out);
}

// Round 19
// 112.184 us; speedup vs baseline: 1.6772x; 1.6772x over previous
//
#include <hip/hip_runtime.h>
#include <math.h>
#include <utility>

#define BATCH 16384
#define INPUT_DIM 512
#define HIDDEN 1024
#define NROT 32
#define NANG 496   // 32*31/2

typedef _Float16 half8 __attribute__((ext_vector_type(8)));
typedef _Float16 half4 __attribute__((ext_vector_type(4)));
typedef float    f32x4 __attribute__((ext_vector_type(4)));

// ---------------------------------------------------------------------------
// Fused prep: x, W1, W2 -> f16 in one launch. W2 zero-padded 496 -> 512 rows
// so GEMM2's B staging needs no bounds checks.
// ---------------------------------------------------------------------------
#define NX8  (BATCH * INPUT_DIM / 8)     // 1048576 half8 units
#define NW18 (HIDDEN * INPUT_DIM / 8)    // 65536
#define NW28 (512 * HIDDEN / 8)          // 65536 (padded)

__global__ __launch_bounds__(256) void prep_f16(
    const float* __restrict__ x, const float* __restrict__ W1,
    const float* __restrict__ W2, _Float16* __restrict__ x16,
    _Float16* __restrict__ W116, _Float16* __restrict__ W216)
{
    const int i = blockIdx.x * 256 + threadIdx.x;
    const float* src; _Float16* dst; int j; bool zero = false;
    if (i < NX8)              { j = i;               src = x;  dst = x16;  }
    else if (i < NX8 + NW18)  { j = i - NX8;         src = W1; dst = W116; }
    else if (i < NX8 + NW18 + NW28) {
        j = i - NX8 - NW18;   src = W2; dst = W216;
        zero = (j * 8 >= NANG * HIDDEN);
    } else return;

    half8 h;
    if (zero) {
        #pragma unroll
        for (int q = 0; q < 8; ++q) h[q] = (_Float16)0.f;
    } else {
        const float4* s = (const float4*)src + (size_t)j * 2;
        const float4 a = s[0], b = s[1];
        h[0]=(_Float16)a.x; h[1]=(_Float16)a.y; h[2]=(_Float16)a.z; h[3]=(_Float16)a.w;
        h[4]=(_Float16)b.x; h[5]=(_Float16)b.y; h[6]=(_Float16)b.z; h[7]=(_Float16)b.w;
    }
    *(half8*)(dst + (size_t)j * 8) = h;
}

// ---------------------------------------------------------------------------
// f16 MFMA GEMM (NT) with global_load_lds staging + XCD-local block remap.
//   - 1D grid; my=(g&7)+8*((g>>3)/GX), mx=(g>>3)%GX: all GX n-blocks of a
//     row-panel run on one XCD -> A panel fetched once per XCD (kills the
//     8x/4x A over-fetch seen in rocprof: 133MB for a 16.8MB A).
//   - Staging: wave w stages A/B rows [32w,32w+32) via 4x global_load_lds
//     width=16 (linear LDS dest = wave base + lane*16; per-lane global src
//     pre-swizzled chunk c^(row&3) -> LDS layout identical to the old
//     reg-staged XOR layout, fragment reads unchanged).
//   EPI=0: relu -> f16 Ch[M][Nout];  EPI=1: theta -> f32 Cf[M][Nout] (<Nout)
// ---------------------------------------------------------------------------
__device__ __forceinline__ void gld16(const void* g, void* l) {
    __builtin_amdgcn_global_load_lds(
        (const __attribute__((address_space(1))) void*)g,
        (__attribute__((address_space(3))) void*)l, 16, 0, 0);
}

template<int EPI>
__global__ __launch_bounds__(256) void gemm_nt_f16(
    const _Float16* __restrict__ A, const _Float16* __restrict__ B,
    const float* __restrict__ bias, float* __restrict__ Cf,
    _Float16* __restrict__ Ch, int M, int K, int Nout, int GX)
{
    constexpr int BK = 32;
    __shared__ _Float16 sA[2][128 * BK];
    __shared__ _Float16 sB[2][128 * BK];

    const int g  = blockIdx.x;
    const int my = (g & 7) + (((g >> 3) / GX) << 3);
    const int mx = (g >> 3) % GX;
    const int m0 = my * 128;
    const int n0 = mx * 128;

    const int tid  = threadIdx.x;
    const int lane = tid & 63;
    const int wid  = tid >> 6;

    // staging: per-lane global addresses (chunk pre-swizzled), uniform LDS base
    const int srow = lane >> 2;                       // row within 16-row seg
    const int schk = (lane & 3) ^ (srow & 3);         // swizzled 8-f16 chunk
    const _Float16* gA0 = A + (size_t)(m0 + wid * 32 + srow) * K + schk * 8;
    const _Float16* gA1 = gA0 + (size_t)16 * K;
    const _Float16* gB0 = B + (size_t)(n0 + wid * 32 + srow) * K + schk * 8;
    const _Float16* gB1 = gB0 + (size_t)16 * K;

    auto stage = [&](int kt, int buf) {
        const size_t ko = (size_t)kt * BK;
        gld16(gA0 + ko, &sA[buf][wid * 1024]);
        gld16(gA1 + ko, &sA[buf][wid * 1024 + 512]);
        gld16(gB0 + ko, &sB[buf][wid * 1024]);
        gld16(gB1 + ko, &sB[buf][wid * 1024 + 512]);
    };

    const int wr = wid >> 1, wc = wid & 1;
    const int fr = lane & 15, fq = lane >> 4;
    const int swR   = ((fq ^ (fr & 3)) << 3);
    const int aBase = (wr * 64 + fr) * BK + swR;
    const int bBase = (wc * 64 + fr) * BK + swR;

    f32x4 acc[4][4];
    #pragma unroll
    for (int i = 0; i < 4; ++i)
        #pragma unroll
        for (int j = 0; j < 4; ++j) acc[i][j] = (f32x4)(0.f);

    const int NT = K / BK;
    stage(0, 0);
    __syncthreads();                       // vmcnt(0) drained at barrier
    int cur = 0;

    for (int kt = 0; kt < NT; ++kt) {
        if (kt + 1 < NT) stage(kt + 1, cur ^ 1);   // in flight across compute

        half8 a_[4], b_[4];
        #pragma unroll
        for (int f = 0; f < 4; ++f) {
            a_[f] = *(const half8*)&sA[cur][aBase + f * 16 * BK];
            b_[f] = *(const half8*)&sB[cur][bBase + f * 16 * BK];
        }
        #pragma unroll
        for (int fm = 0; fm < 4; ++fm)
            #pragma unroll
            for (int fn = 0; fn < 4; ++fn)
                acc[fm][fn] = __builtin_amdgcn_mfma_f32_16x16x32_f16(
                    a_[fm], b_[fn], acc[fm][fn], 0, 0, 0);

        __syncthreads();                   // drains next-tile loads + our reads
        cur ^= 1;
    }

    if (EPI == 0) {
        #pragma unroll
        for (int fn = 0; fn < 4; ++fn) {
            const int col = n0 + wc * 64 + fn * 16 + fr;
            const float bv = bias[col];
            #pragma unroll
            for (int fm = 0; fm < 4; ++fm) {
                const int row0 = m0 + wr * 64 + fm * 16 + fq * 4;
                #pragma unroll
                for (int r = 0; r < 4; ++r)
                    Ch[(size_t)(row0 + r) * Nout + col] =
                        (_Float16)fmaxf(acc[fm][fn][r] + bv, 0.f);
            }
        }
    } else {
        #pragma unroll
        for (int fn = 0; fn < 4; ++fn) {
            const int col = n0 + wc * 64 + fn * 16 + fr;
            if (col < Nout) {
                const float bv = bias[col];
                #pragma unroll
                for (int fm = 0; fm < 4; ++fm) {
                    const int row0 = m0 + wr * 64 + fm * 16 + fq * 4;
                    #pragma unroll
                    for (int r = 0; r < 4; ++r)
                        Cf[(size_t)(row0 + r) * Nout + col] = acc[fm][fn][r] + bv;
                }
            }
        }
    }
}

// ---------------------------------------------------------------------------
// Rotate — EXACT revert to the round-15 kernel (passed, 61us): 4 chunks of
// 124 (row chains even / column chains odd), f32 cs staged from theta with
// one sincos, verified L1/L2 MFMA tree, 24KB LDS overlays.
// ---------------------------------------------------------------------------
struct IJTbl { unsigned char i[NANG]; unsigned char j[NANG]; };
constexpr IJTbl make_ij_tbl() {
    IJTbl t{};
    int k = 0;
    for (int i = 0; i < NROT - 1; ++i)
        for (int j = i + 1; j < NROT; ++j) { t.i[k] = (unsigned char)i; t.j[k] = (unsigned char)j; ++k; }
    return t;
}
constexpr IJTbl IJT = make_ij_tbl();

#define EVEN_H 4096    // f16 index of even-factor region (= f32 2048)
#define ODD_H  8192    // f16 index of odd-factor region  (= f32 4096)
#define PCM_H  0       // f16 index of P region (column-major D stores)
#define RF32   2048    // f32 index of R output region

template<int M>   // forward: rotations 2M then 2M+1 (row rule)
__device__ __forceinline__ void rot_fwd(const f32x4 q, float (&v)[NROT]) {
    {
        constexpr int k = 2 * M;
        constexpr int i = IJT.i[k], j = IJT.j[k];
        const float vi = v[i], vj = v[j];
        v[i] = fmaf(q[0], vi,  q[1] * vj);
        v[j] = fmaf(q[0], vj, -q[1] * vi);
    }
    {
        constexpr int k = 2 * M + 1;
        constexpr int i = IJT.i[k], j = IJT.j[k];
        const float vi = v[i], vj = v[j];
        v[i] = fmaf(q[2], vi,  q[3] * vj);
        v[j] = fmaf(q[2], vj, -q[3] * vi);
    }
}

template<int M>   // reverse: rotations 2M+1 then 2M (column rule)
__device__ __forceinline__ void rot_rev(const f32x4 q, float (&v)[NROT]) {
    {
        constexpr int k = 2 * M + 1;
        constexpr int i = IJT.i[k], j = IJT.j[k];
        const float vi = v[i], vj = v[j];
        v[i] = fmaf(q[2], vi, -q[3] * vj);
        v[j] = fmaf(q[2], vj,  q[3] * vi);
    }
    {
        constexpr int k = 2 * M;
        constexpr int i = IJT.i[k], j = IJT.j[k];
        const float vi = v[i], vj = v[j];
        v[i] = fmaf(q[0], vi, -q[1] * vj);
        v[j] = fmaf(q[0], vj,  q[1] * vi);
    }
}

template<int W, int T>
__device__ __forceinline__ void chain_step(const float* __restrict__ lcs,
                                           float (&v)[NROT]) {
    if constexpr ((W & 1) == 0) {
        constexpr int fi = 62 * W + T;                 // forward order
        const f32x4 q = *(const f32x4*)(lcs + fi * 4);
        rot_fwd<fi>(q, v);
    } else {
        constexpr int fi = 62 * W + (61 - T);          // reverse order
        const f32x4 q = *(const f32x4*)(lcs + fi * 4);
        rot_rev<fi>(q, v);
    }
}

template<int W, size_t... Ts>
__device__ __forceinline__ void chain_runW(const float* __restrict__ lcs,
                                           float (&v)[NROT],
                                           std::index_sequence<Ts...>) {
    (chain_step<W, (int)Ts>(lcs, v), ...);
}

template<int W>
__device__ __forceinline__ void chain_and_store(const float* __restrict__ lcs,
                                                _Float16* __restrict__ lh,
                                                int half, int r) {
    float v[NROT];
    #pragma unroll
    for (int c = 0; c < NROT; ++c) v[c] = (c == r) ? 1.f : 0.f;
    chain_runW<W>(lcs, v, std::make_index_sequence<62>{});

    constexpr int REG = ((W & 1) == 0) ? EVEN_H : ODD_H;
    const int base = REG + (half * 2 + (W >> 1)) * 1024;
    #pragma unroll
    for (int kq = 0; kq < 4; ++kq) {
        half8 hv;
        #pragma unroll
        for (int j = 0; j < 8; ++j) hv[j] = (_Float16)v[kq * 8 + j];
        *(half8*)&lh[base + r * 32 + ((kq ^ (r & 3)) << 3)] = hv;
    }
}

__global__ __launch_bounds__(256) void rotate_kernel(
    const float* __restrict__ theta, float* __restrict__ out)
{
    __shared__ float smem[6144];   // 24 KB
    _Float16* lh = (_Float16*)smem;

    const int tid  = threadIdx.x;
    const int wid  = tid >> 6;
    const int lane = tid & 63;
    const int half = (tid >> 5) & 1;       // batch within block (chain phase)
    const int r    = tid & 31;             // row / column index
    const int fr = lane & 15, fq = lane >> 4;
    const size_t b0 = (size_t)blockIdx.x * 2;

    // ---- stage: load theta, sincos once, write (c,s) pairs ----
    if (tid < 248) {
        const f32x4 th = *(const f32x4*)(theta + b0 * NANG + tid * 4);
        f32x4 p0, p1;
        float s, c;
        __sincosf(th[0], &s, &c); p0[0] = c; p0[1] = s;
        __sincosf(th[1], &s, &c); p0[2] = c; p0[3] = s;
        __sincosf(th[2], &s, &c); p1[0] = c; p1[1] = s;
        __sincosf(th[3], &s, &c); p1[2] = c; p1[3] = s;
        *(f32x4*)&smem[tid * 8]     = p0;
        *(f32x4*)&smem[tid * 8 + 4] = p1;
    }
    __syncthreads();

    // ---- chunk chains (wave-uniform branch) ----
    const float* lcs = smem + half * 992;
    if      (wid == 0) chain_and_store<0>(lcs, lh, half, r);
    else if (wid == 1) chain_and_store<1>(lcs, lh, half, r);
    else if (wid == 2) chain_and_store<2>(lcs, lh, half, r);
    else               chain_and_store<3>(lcs, lh, half, r);
    __syncthreads();

    // ---- L1: wave (ba,pi) ----
    //  pi=0: D = mfma(C1^T, C0)  = P0^T  -> col-major store => PCM0 = P0 rows
    //  pi=1: D = mfma(C2, C3^T)  = P1    -> col-major store => PCM1 = P1^T rows
    {
        const int ba = wid >> 1, pi = wid & 1;
        const int Eb = EVEN_H + (ba * 2 + pi) * 1024;   // C_{2pi} rows
        const int Ob = ODD_H  + (ba * 2 + pi) * 1024;   // C_{2pi+1}^T rows
        const int Asrc = (pi == 0) ? Ob : Eb;
        const int Bsrc = (pi == 0) ? Eb : Ob;
        const int swz = (fq ^ (fr & 3)) << 3;
        half8 a[2], b[2];
        #pragma unroll
        for (int mi = 0; mi < 2; ++mi) {
            a[mi] = *(const half8*)&lh[Asrc + (mi * 16 + fr) * 32 + swz];
            b[mi] = *(const half8*)&lh[Bsrc + (mi * 16 + fr) * 32 + swz];
        }
        const int Pb = PCM_H + (ba * 2 + pi) * 1024;
        #pragma unroll
        for (int mi = 0; mi < 2; ++mi)
            #pragma unroll
            for (int ni = 0; ni < 2; ++ni) {
                const f32x4 d = __builtin_amdgcn_mfma_f32_16x16x32_f16(
                    a[mi], b[ni], (f32x4)(0.f), 0, 0, 0);
                half4 hv;
                #pragma unroll
                for (int q = 0; q < 4; ++q) hv[q] = (_Float16)d[q];
                const int col  = ni * 16 + fr;
                const int rowb = (mi * 16 + fq * 4) ^ ((col & 3) << 3);
                *(half4*)&lh[Pb + col * 32 + rowb] = hv;
            }
    }
    __syncthreads();

    // ---- L2: D = mfma(PCM1, PCM0) = P1^T @ P0^T = R^T; lane holds 4
    //      consecutive COLUMNS of R at fixed row -> b128 stores.
    {
        const int ba = wid >> 1, mi = wid & 1;
        const int Ab = PCM_H + (ba * 2 + 1) * 1024;   // P1^T rows
        const int Bb = PCM_H + (ba * 2 + 0) * 1024;   // P0 rows
        const int swz = (fq ^ (fr & 3)) << 3;
        const half8 a = *(const half8*)&lh[Ab + (mi * 16 + fr) * 32 + swz];
        #pragma unroll
        for (int ni = 0; ni < 2; ++ni) {
            const half8 b = *(const half8*)&lh[Bb + (ni * 16 + fr) * 32 + swz];
            const f32x4 d = __builtin_amdgcn_mfma_f32_16x16x32_f16(
                a, b, (f32x4)(0.f), 0, 0, 0);
            const int row  = ni * 16 + fr;            // row of R
            const int colq = mi * 4 + fq;             // col block (4 f32)
            *(f32x4*)&smem[RF32 + ba * 1024 + row * 32 + ((colq ^ (row & 7)) << 2)] = d;
        }
    }
    __syncthreads();

    // ---- coalesced copy-out ----
    #pragma unroll
    for (int s = 0; s < 2; ++s) {
        const int idx = s * 256 + tid;
        const int ba  = idx >> 8;
        const int f4i = idx & 255;
        const int row = f4i >> 3;
        const int cc  = f4i & 7;
        const f32x4 val =
            *(const f32x4*)&smem[RF32 + ba * 1024 + row * 32 + ((cc ^ (row & 7)) << 2)];
        *(f32x4*)(out + (b0 + ba) * 1024 + (size_t)f4i * 4) = val;
    }
}

// ---------------------------------------------------------------------------
extern "C" void kernel_launch(void* const* d_in, const int* in_sizes, int n_in,
                              void* d_out, int out_size, void* d_ws, size_t ws_size,
                              hipStream_t stream)
{
    const float* x  = (const float*)d_in[0];   // [16384, 512]
    const float* W1 = (const float*)d_in[1];   // [1024, 512]
    const float* b1 = (const float*)d_in[2];   // [1024]
    const float* W2 = (const float*)d_in[3];   // [496, 1024]
    const float* b2 = (const float*)d_in[4];   // [496]
    float* out = (float*)d_out;                // [16384, 32, 32]

    // d_out (67.1 MB) doubles as f16 scratch; rotate rewrites all of it last.
    _Float16* h16  = (_Float16*)d_out;               // 33.55 MB
    _Float16* x16  = h16  + (size_t)BATCH * HIDDEN;  // 16.78 MB
    _Float16* W116 = x16  + (size_t)BATCH * INPUT_DIM;   // 1 MB
    _Float16* W216 = W116 + (size_t)HIDDEN * INPUT_DIM;  // 1 MB (512-row pad)
    float*    th   = (float*)d_ws;                   // theta [16384][496] f32

    // fused prep: x, W1, W2(padded) -> f16, one launch
    prep_f16<<<dim3((NX8 + NW18 + NW28) / 256), 256, 0, stream>>>(
        x, W1, W2, x16, W116, W216);

    // h16 = f16(relu(x @ W1^T + b1));  grid 1D = 8 * 128
    gemm_nt_f16<0><<<dim3(8 * 128), 256, 0, stream>>>(
        x16, W116, b1, nullptr, h16, BATCH, INPUT_DIM, HIDDEN, 8);

    // th = h16 @ W2^T + b2;  grid 1D = 4 * 128
    gemm_nt_f16<1><<<dim3(4 * 128), 256, 0, stream>>>(
        h16, W216, b2, th, nullptr, BATCH, HIDDEN, NANG, 4);

    rotate_kernel<<<dim3(BATCH / 2), 256, 0, stream>>>(th, out);
}

// Round 20
// 112.043 us; speedup vs baseline: 1.6793x; 1.0013x over previous
//
#include <hip/hip_runtime.h>
#include <math.h>
#include <utility>

#define BATCH 16384
#define INPUT_DIM 512
#define HIDDEN 1024
#define NROT 32
#define NANG 496   // 32*31/2

typedef _Float16 half8 __attribute__((ext_vector_type(8)));
typedef _Float16 half4 __attribute__((ext_vector_type(4)));
typedef float    f32x4 __attribute__((ext_vector_type(4)));

// ---------------------------------------------------------------------------
// Fused prep: x, W1, W2 -> f16 in one launch. W2 zero-padded 496 -> 512 rows.
// ---------------------------------------------------------------------------
#define NX8  (BATCH * INPUT_DIM / 8)
#define NW18 (HIDDEN * INPUT_DIM / 8)
#define NW28 (512 * HIDDEN / 8)

__global__ __launch_bounds__(256) void prep_f16(
    const float* __restrict__ x, const float* __restrict__ W1,
    const float* __restrict__ W2, _Float16* __restrict__ x16,
    _Float16* __restrict__ W116, _Float16* __restrict__ W216)
{
    const int i = blockIdx.x * 256 + threadIdx.x;
    const float* src; _Float16* dst; int j; bool zero = false;
    if (i < NX8)              { j = i;               src = x;  dst = x16;  }
    else if (i < NX8 + NW18)  { j = i - NX8;         src = W1; dst = W116; }
    else if (i < NX8 + NW18 + NW28) {
        j = i - NX8 - NW18;   src = W2; dst = W216;
        zero = (j * 8 >= NANG * HIDDEN);
    } else return;

    half8 h;
    if (zero) {
        #pragma unroll
        for (int q = 0; q < 8; ++q) h[q] = (_Float16)0.f;
    } else {
        const float4* s = (const float4*)src + (size_t)j * 2;
        const float4 a = s[0], b = s[1];
        h[0]=(_Float16)a.x; h[1]=(_Float16)a.y; h[2]=(_Float16)a.z; h[3]=(_Float16)a.w;
        h[4]=(_Float16)b.x; h[5]=(_Float16)b.y; h[6]=(_Float16)b.z; h[7]=(_Float16)b.w;
    }
    *(half8*)(dst + (size_t)j * 8) = h;
}

// ---------------------------------------------------------------------------
// f16 MFMA GEMM (NT), global_load_lds staging + XCD-local remap (R19, passing)
// ---------------------------------------------------------------------------
__device__ __forceinline__ void gld16(const void* g, void* l) {
    __builtin_amdgcn_global_load_lds(
        (const __attribute__((address_space(1))) void*)g,
        (__attribute__((address_space(3))) void*)l, 16, 0, 0);
}

template<int EPI>
__global__ __launch_bounds__(256) void gemm_nt_f16(
    const _Float16* __restrict__ A, const _Float16* __restrict__ B,
    const float* __restrict__ bias, float* __restrict__ Cf,
    _Float16* __restrict__ Ch, int M, int K, int Nout, int GX)
{
    constexpr int BK = 32;
    __shared__ _Float16 sA[2][128 * BK];
    __shared__ _Float16 sB[2][128 * BK];

    const int g  = blockIdx.x;
    const int my = (g & 7) + (((g >> 3) / GX) << 3);
    const int mx = (g >> 3) % GX;
    const int m0 = my * 128;
    const int n0 = mx * 128;

    const int tid  = threadIdx.x;
    const int lane = tid & 63;
    const int wid  = tid >> 6;

    const int srow = lane >> 2;
    const int schk = (lane & 3) ^ (srow & 3);
    const _Float16* gA0 = A + (size_t)(m0 + wid * 32 + srow) * K + schk * 8;
    const _Float16* gA1 = gA0 + (size_t)16 * K;
    const _Float16* gB0 = B + (size_t)(n0 + wid * 32 + srow) * K + schk * 8;
    const _Float16* gB1 = gB0 + (size_t)16 * K;

    auto stage = [&](int kt, int buf) {
        const size_t ko = (size_t)kt * BK;
        gld16(gA0 + ko, &sA[buf][wid * 1024]);
        gld16(gA1 + ko, &sA[buf][wid * 1024 + 512]);
        gld16(gB0 + ko, &sB[buf][wid * 1024]);
        gld16(gB1 + ko, &sB[buf][wid * 1024 + 512]);
    };

    const int wr = wid >> 1, wc = wid & 1;
    const int fr = lane & 15, fq = lane >> 4;
    const int swR   = ((fq ^ (fr & 3)) << 3);
    const int aBase = (wr * 64 + fr) * BK + swR;
    const int bBase = (wc * 64 + fr) * BK + swR;

    f32x4 acc[4][4];
    #pragma unroll
    for (int i = 0; i < 4; ++i)
        #pragma unroll
        for (int j = 0; j < 4; ++j) acc[i][j] = (f32x4)(0.f);

    const int NT = K / BK;
    stage(0, 0);
    __syncthreads();
    int cur = 0;

    for (int kt = 0; kt < NT; ++kt) {
        if (kt + 1 < NT) stage(kt + 1, cur ^ 1);

        half8 a_[4], b_[4];
        #pragma unroll
        for (int f = 0; f < 4; ++f) {
            a_[f] = *(const half8*)&sA[cur][aBase + f * 16 * BK];
            b_[f] = *(const half8*)&sB[cur][bBase + f * 16 * BK];
        }
        #pragma unroll
        for (int fm = 0; fm < 4; ++fm)
            #pragma unroll
            for (int fn = 0; fn < 4; ++fn)
                acc[fm][fn] = __builtin_amdgcn_mfma_f32_16x16x32_f16(
                    a_[fm], b_[fn], acc[fm][fn], 0, 0, 0);

        __syncthreads();
        cur ^= 1;
    }

    if (EPI == 0) {
        #pragma unroll
        for (int fn = 0; fn < 4; ++fn) {
            const int col = n0 + wc * 64 + fn * 16 + fr;
            const float bv = bias[col];
            #pragma unroll
            for (int fm = 0; fm < 4; ++fm) {
                const int row0 = m0 + wr * 64 + fm * 16 + fq * 4;
                #pragma unroll
                for (int r = 0; r < 4; ++r)
                    Ch[(size_t)(row0 + r) * Nout + col] =
                        (_Float16)fmaxf(acc[fm][fn][r] + bv, 0.f);
            }
        }
    } else {
        #pragma unroll
        for (int fn = 0; fn < 4; ++fn) {
            const int col = n0 + wc * 64 + fn * 16 + fr;
            if (col < Nout) {
                const float bv = bias[col];
                #pragma unroll
                for (int fm = 0; fm < 4; ++fm) {
                    const int row0 = m0 + wr * 64 + fm * 16 + fq * 4;
                    #pragma unroll
                    for (int r = 0; r < 4; ++r)
                        Cf[(size_t)(row0 + r) * Nout + col] = acc[fm][fn][r] + bv;
                }
            }
        }
    }
}

// ---------------------------------------------------------------------------
// Rotate — R15/R19 structure with BANK-CONFLICT PADS (math byte-identical):
//   every per-batch slot stride was a multiple of 128B, putting the two
//   half-waves of each ds op in the same bank quad (R19: 4.05M conflict cyc).
//   Pads: cs 992->1000 f32/batch; factor & PCM slots 1024->1040 f16
//   (bank shift 8); R slots 1024->1032 f32.
// LDS map (f16 units): cs [0,4000) (PCM overlays [0,4160) after chains);
// EVEN [4224, 8384); ODD [8448, 12608); R f32 [2112, 4176) overlays EVEN
// after L1. Total 25216 B.
// ---------------------------------------------------------------------------
struct IJTbl { unsigned char i[NANG]; unsigned char j[NANG]; };
constexpr IJTbl make_ij_tbl() {
    IJTbl t{};
    int k = 0;
    for (int i = 0; i < NROT - 1; ++i)
        for (int j = i + 1; j < NROT; ++j) { t.i[k] = (unsigned char)i; t.j[k] = (unsigned char)j; ++k; }
    return t;
}
constexpr IJTbl IJT = make_ij_tbl();

#define CS_STRIDE 1000   // f32 per-batch cs stride (was 992)
#define SLOT_H    1040   // f16 per-slot stride for factors/PCM (was 1024)
#define EVEN_H    4224   // f16 base of even-factor region
#define ODD_H     8448   // f16 base of odd-factor region
#define PCM_H     0      // f16 base of P region (overlays cs)
#define RF32      2112   // f32 base of R region (overlays EVEN)
#define R_STRIDE  1032   // f32 per-batch R stride (was 1024)

template<int M>   // forward: rotations 2M then 2M+1 (row rule)
__device__ __forceinline__ void rot_fwd(const f32x4 q, float (&v)[NROT]) {
    {
        constexpr int k = 2 * M;
        constexpr int i = IJT.i[k], j = IJT.j[k];
        const float vi = v[i], vj = v[j];
        v[i] = fmaf(q[0], vi,  q[1] * vj);
        v[j] = fmaf(q[0], vj, -q[1] * vi);
    }
    {
        constexpr int k = 2 * M + 1;
        constexpr int i = IJT.i[k], j = IJT.j[k];
        const float vi = v[i], vj = v[j];
        v[i] = fmaf(q[2], vi,  q[3] * vj);
        v[j] = fmaf(q[2], vj, -q[3] * vi);
    }
}

template<int M>   // reverse: rotations 2M+1 then 2M (column rule)
__device__ __forceinline__ void rot_rev(const f32x4 q, float (&v)[NROT]) {
    {
        constexpr int k = 2 * M + 1;
        constexpr int i = IJT.i[k], j = IJT.j[k];
        const float vi = v[i], vj = v[j];
        v[i] = fmaf(q[2], vi, -q[3] * vj);
        v[j] = fmaf(q[2], vj,  q[3] * vi);
    }
    {
        constexpr int k = 2 * M;
        constexpr int i = IJT.i[k], j = IJT.j[k];
        const float vi = v[i], vj = v[j];
        v[i] = fmaf(q[0], vi, -q[1] * vj);
        v[j] = fmaf(q[0], vj,  q[1] * vi);
    }
}

template<int W, int T>
__device__ __forceinline__ void chain_step(const float* __restrict__ lcs,
                                           float (&v)[NROT]) {
    if constexpr ((W & 1) == 0) {
        constexpr int fi = 62 * W + T;
        const f32x4 q = *(const f32x4*)(lcs + fi * 4);
        rot_fwd<fi>(q, v);
    } else {
        constexpr int fi = 62 * W + (61 - T);
        const f32x4 q = *(const f32x4*)(lcs + fi * 4);
        rot_rev<fi>(q, v);
    }
}

template<int W, size_t... Ts>
__device__ __forceinline__ void chain_runW(const float* __restrict__ lcs,
                                           float (&v)[NROT],
                                           std::index_sequence<Ts...>) {
    (chain_step<W, (int)Ts>(lcs, v), ...);
}

template<int W>
__device__ __forceinline__ void chain_and_store(const float* __restrict__ lcs,
                                                _Float16* __restrict__ lh,
                                                int half, int r) {
    float v[NROT];
    #pragma unroll
    for (int c = 0; c < NROT; ++c) v[c] = (c == r) ? 1.f : 0.f;
    chain_runW<W>(lcs, v, std::make_index_sequence<62>{});

    constexpr int REG = ((W & 1) == 0) ? EVEN_H : ODD_H;
    const int base = REG + (half * 2 + (W >> 1)) * SLOT_H;
    #pragma unroll
    for (int kq = 0; kq < 4; ++kq) {
        half8 hv;
        #pragma unroll
        for (int j = 0; j < 8; ++j) hv[j] = (_Float16)v[kq * 8 + j];
        *(half8*)&lh[base + r * 32 + ((kq ^ (r & 3)) << 3)] = hv;
    }
}

__global__ __launch_bounds__(256) void rotate_kernel(
    const float* __restrict__ theta, float* __restrict__ out)
{
    __shared__ float smem[6304];   // 25,216 B
    _Float16* lh = (_Float16*)smem;

    const int tid  = threadIdx.x;
    const int wid  = tid >> 6;
    const int lane = tid & 63;
    const int half = (tid >> 5) & 1;
    const int r    = tid & 31;
    const int fr = lane & 15, fq = lane >> 4;
    const size_t b0 = (size_t)blockIdx.x * 2;

    // ---- stage: theta -> sincos -> (c,s) f32 pairs, padded per-batch base ----
    if (tid < 248) {
        const int b   = tid >= 124;
        const int idx = tid - b * 124;
        const f32x4 th = *(const f32x4*)(theta + b0 * NANG + (size_t)(b * NANG) + idx * 4);
        f32x4 p0, p1;
        float s, c;
        __sincosf(th[0], &s, &c); p0[0] = c; p0[1] = s;
        __sincosf(th[1], &s, &c); p0[2] = c; p0[3] = s;
        __sincosf(th[2], &s, &c); p1[0] = c; p1[1] = s;
        __sincosf(th[3], &s, &c); p1[2] = c; p1[3] = s;
        const int base = b * CS_STRIDE + idx * 8;
        *(f32x4*)&smem[base]     = p0;
        *(f32x4*)&smem[base + 4] = p1;
    }
    __syncthreads();

    // ---- chunk chains (wave-uniform branch) ----
    const float* lcs = smem + half * CS_STRIDE;
    if      (wid == 0) chain_and_store<0>(lcs, lh, half, r);
    else if (wid == 1) chain_and_store<1>(lcs, lh, half, r);
    else if (wid == 2) chain_and_store<2>(lcs, lh, half, r);
    else               chain_and_store<3>(lcs, lh, half, r);
    __syncthreads();

    // ---- L1: wave (ba,pi) ----
    //  pi=0: D = mfma(C1^T, C0)  = P0^T  -> col-major store => PCM0 = P0 rows
    //  pi=1: D = mfma(C2, C3^T)  = P1    -> col-major store => PCM1 = P1^T rows
    {
        const int ba = wid >> 1, pi = wid & 1;
        const int Eb = EVEN_H + (ba * 2 + pi) * SLOT_H;
        const int Ob = ODD_H  + (ba * 2 + pi) * SLOT_H;
        const int Asrc = (pi == 0) ? Ob : Eb;
        const int Bsrc = (pi == 0) ? Eb : Ob;
        const int swz = (fq ^ (fr & 3)) << 3;
        half8 a[2], b[2];
        #pragma unroll
        for (int mi = 0; mi < 2; ++mi) {
            a[mi] = *(const half8*)&lh[Asrc + (mi * 16 + fr) * 32 + swz];
            b[mi] = *(const half8*)&lh[Bsrc + (mi * 16 + fr) * 32 + swz];
        }
        const int Pb = PCM_H + (ba * 2 + pi) * SLOT_H;
        #pragma unroll
        for (int mi = 0; mi < 2; ++mi)
            #pragma unroll
            for (int ni = 0; ni < 2; ++ni) {
                const f32x4 d = __builtin_amdgcn_mfma_f32_16x16x32_f16(
                    a[mi], b[ni], (f32x4)(0.f), 0, 0, 0);
                half4 hv;
                #pragma unroll
                for (int q = 0; q < 4; ++q) hv[q] = (_Float16)d[q];
                const int col  = ni * 16 + fr;
                const int rowb = (mi * 16 + fq * 4) ^ ((col & 3) << 3);
                *(half4*)&lh[Pb + col * 32 + rowb] = hv;
            }
    }
    __syncthreads();

    // ---- L2: D = mfma(PCM1, PCM0) = P1^T @ P0^T = R^T ----
    {
        const int ba = wid >> 1, mi = wid & 1;
        const int Ab = PCM_H + (ba * 2 + 1) * SLOT_H;
        const int Bb = PCM_H + (ba * 2 + 0) * SLOT_H;
        const int swz = (fq ^ (fr & 3)) << 3;
        const half8 a = *(const half8*)&lh[Ab + (mi * 16 + fr) * 32 + swz];
        #pragma unroll
        for (int ni = 0; ni < 2; ++ni) {
            const half8 b = *(const half8*)&lh[Bb + (ni * 16 + fr) * 32 + swz];
            const f32x4 d = __builtin_amdgcn_mfma_f32_16x16x32_f16(
                a, b, (f32x4)(0.f), 0, 0, 0);
            const int row  = ni * 16 + fr;
            const int colq = mi * 4 + fq;
            *(f32x4*)&smem[RF32 + ba * R_STRIDE + row * 32 + ((colq ^ (row & 7)) << 2)] = d;
        }
    }
    __syncthreads();

    // ---- coalesced copy-out ----
    #pragma unroll
    for (int s = 0; s < 2; ++s) {
        const int idx = s * 256 + tid;
        const int ba  = idx >> 8;
        const int f4i = idx & 255;
        const int row = f4i >> 3;
        const int cc  = f4i & 7;
        const f32x4 val =
            *(const f32x4*)&smem[RF32 + ba * R_STRIDE + row * 32 + ((cc ^ (row & 7)) << 2)];
        *(f32x4*)(out + (b0 + ba) * 1024 + (size_t)f4i * 4) = val;
    }
}

// ---------------------------------------------------------------------------
extern "C" void kernel_launch(void* const* d_in, const int* in_sizes, int n_in,
                              void* d_out, int out_size, void* d_ws, size_t ws_size,
                              hipStream_t stream)
{
    const float* x  = (const float*)d_in[0];   // [16384, 512]
    const float* W1 = (const float*)d_in[1];   // [1024, 512]
    const float* b1 = (const float*)d_in[2];   // [1024]
    const float* W2 = (const float*)d_in[3];   // [496, 1024]
    const float* b2 = (const float*)d_in[4];   // [496]
    float* out = (float*)d_out;                // [16384, 32, 32]

    _Float16* h16  = (_Float16*)d_out;
    _Float16* x16  = h16  + (size_t)BATCH * HIDDEN;
    _Float16* W116 = x16  + (size_t)BATCH * INPUT_DIM;
    _Float16* W216 = W116 + (size_t)HIDDEN * INPUT_DIM;
    float*    th   = (float*)d_ws;

    prep_f16<<<dim3((NX8 + NW18 + NW28) / 256), 256, 0, stream>>>(
        x, W1, W2, x16, W116, W216);

    gemm_nt_f16<0><<<dim3(8 * 128), 256, 0, stream>>>(
        x16, W116, b1, nullptr, h16, BATCH, INPUT_DIM, HIDDEN, 8);

    gemm_nt_f16<1><<<dim3(4 * 128), 256, 0, stream>>>(
        h16, W216, b2, th, nullptr, BATCH, HIDDEN, NANG, 4);

    rotate_kernel<<<dim3(BATCH / 2), 256, 0, stream>>>(th, out);
}

// Round 21
// 104.783 us; speedup vs baseline: 1.7957x; 1.0693x over previous
//
#include <hip/hip_runtime.h>
#include <math.h>
#include <utility>

#define BATCH 16384
#define INPUT_DIM 512
#define HIDDEN 1024
#define NROT 32
#define NANG 496   // 32*31/2

typedef _Float16 half8 __attribute__((ext_vector_type(8)));
typedef _Float16 half4 __attribute__((ext_vector_type(4)));
typedef float    f32x4 __attribute__((ext_vector_type(4)));
typedef float    f32x2 __attribute__((ext_vector_type(2)));

// ---------------------------------------------------------------------------
// Fused prep: x, W1, W2 -> f16 in one launch. W2 zero-padded 496 -> 512 rows.
// ---------------------------------------------------------------------------
#define NX8  (BATCH * INPUT_DIM / 8)
#define NW18 (HIDDEN * INPUT_DIM / 8)
#define NW28 (512 * HIDDEN / 8)

__global__ __launch_bounds__(256) void prep_f16(
    const float* __restrict__ x, const float* __restrict__ W1,
    const float* __restrict__ W2, _Float16* __restrict__ x16,
    _Float16* __restrict__ W116, _Float16* __restrict__ W216)
{
    const int i = blockIdx.x * 256 + threadIdx.x;
    const float* src; _Float16* dst; int j; bool zero = false;
    if (i < NX8)              { j = i;               src = x;  dst = x16;  }
    else if (i < NX8 + NW18)  { j = i - NX8;         src = W1; dst = W116; }
    else if (i < NX8 + NW18 + NW28) {
        j = i - NX8 - NW18;   src = W2; dst = W216;
        zero = (j * 8 >= NANG * HIDDEN);
    } else return;

    half8 h;
    if (zero) {
        #pragma unroll
        for (int q = 0; q < 8; ++q) h[q] = (_Float16)0.f;
    } else {
        const float4* s = (const float4*)src + (size_t)j * 2;
        const float4 a = s[0], b = s[1];
        h[0]=(_Float16)a.x; h[1]=(_Float16)a.y; h[2]=(_Float16)a.z; h[3]=(_Float16)a.w;
        h[4]=(_Float16)b.x; h[5]=(_Float16)b.y; h[6]=(_Float16)b.z; h[7]=(_Float16)b.w;
    }
    *(half8*)(dst + (size_t)j * 8) = h;
}

// ---------------------------------------------------------------------------
// f16 MFMA GEMM (NT), global_load_lds staging + XCD-local remap (R19/20 pass)
// ---------------------------------------------------------------------------
__device__ __forceinline__ void gld16(const void* g, void* l) {
    __builtin_amdgcn_global_load_lds(
        (const __attribute__((address_space(1))) void*)g,
        (__attribute__((address_space(3))) void*)l, 16, 0, 0);
}

template<int EPI>
__global__ __launch_bounds__(256) void gemm_nt_f16(
    const _Float16* __restrict__ A, const _Float16* __restrict__ B,
    const float* __restrict__ bias, float* __restrict__ Cf,
    _Float16* __restrict__ Ch, int M, int K, int Nout, int GX)
{
    constexpr int BK = 32;
    __shared__ _Float16 sA[2][128 * BK];
    __shared__ _Float16 sB[2][128 * BK];

    const int g  = blockIdx.x;
    const int my = (g & 7) + (((g >> 3) / GX) << 3);
    const int mx = (g >> 3) % GX;
    const int m0 = my * 128;
    const int n0 = mx * 128;

    const int tid  = threadIdx.x;
    const int lane = tid & 63;
    const int wid  = tid >> 6;

    const int srow = lane >> 2;
    const int schk = (lane & 3) ^ (srow & 3);
    const _Float16* gA0 = A + (size_t)(m0 + wid * 32 + srow) * K + schk * 8;
    const _Float16* gA1 = gA0 + (size_t)16 * K;
    const _Float16* gB0 = B + (size_t)(n0 + wid * 32 + srow) * K + schk * 8;
    const _Float16* gB1 = gB0 + (size_t)16 * K;

    auto stage = [&](int kt, int buf) {
        const size_t ko = (size_t)kt * BK;
        gld16(gA0 + ko, &sA[buf][wid * 1024]);
        gld16(gA1 + ko, &sA[buf][wid * 1024 + 512]);
        gld16(gB0 + ko, &sB[buf][wid * 1024]);
        gld16(gB1 + ko, &sB[buf][wid * 1024 + 512]);
    };

    const int wr = wid >> 1, wc = wid & 1;
    const int fr = lane & 15, fq = lane >> 4;
    const int swR   = ((fq ^ (fr & 3)) << 3);
    const int aBase = (wr * 64 + fr) * BK + swR;
    const int bBase = (wc * 64 + fr) * BK + swR;

    f32x4 acc[4][4];
    #pragma unroll
    for (int i = 0; i < 4; ++i)
        #pragma unroll
        for (int j = 0; j < 4; ++j) acc[i][j] = (f32x4)(0.f);

    const int NT = K / BK;
    stage(0, 0);
    __syncthreads();
    int cur = 0;

    for (int kt = 0; kt < NT; ++kt) {
        if (kt + 1 < NT) stage(kt + 1, cur ^ 1);

        half8 a_[4], b_[4];
        #pragma unroll
        for (int f = 0; f < 4; ++f) {
            a_[f] = *(const half8*)&sA[cur][aBase + f * 16 * BK];
            b_[f] = *(const half8*)&sB[cur][bBase + f * 16 * BK];
        }
        #pragma unroll
        for (int fm = 0; fm < 4; ++fm)
            #pragma unroll
            for (int fn = 0; fn < 4; ++fn)
                acc[fm][fn] = __builtin_amdgcn_mfma_f32_16x16x32_f16(
                    a_[fm], b_[fn], acc[fm][fn], 0, 0, 0);

        __syncthreads();
        cur ^= 1;
    }

    if (EPI == 0) {
        #pragma unroll
        for (int fn = 0; fn < 4; ++fn) {
            const int col = n0 + wc * 64 + fn * 16 + fr;
            const float bv = bias[col];
            #pragma unroll
            for (int fm = 0; fm < 4; ++fm) {
                const int row0 = m0 + wr * 64 + fm * 16 + fq * 4;
                #pragma unroll
                for (int r = 0; r < 4; ++r)
                    Ch[(size_t)(row0 + r) * Nout + col] =
                        (_Float16)fmaxf(acc[fm][fn][r] + bv, 0.f);
            }
        }
    } else {
        #pragma unroll
        for (int fn = 0; fn < 4; ++fn) {
            const int col = n0 + wc * 64 + fn * 16 + fr;
            if (col < Nout) {
                const float bv = bias[col];
                #pragma unroll
                for (int fm = 0; fm < 4; ++fm) {
                    const int row0 = m0 + wr * 64 + fm * 16 + fq * 4;
                    #pragma unroll
                    for (int r = 0; r < 4; ++r)
                        Cf[(size_t)(row0 + r) * Nout + col] = acc[fm][fn][r] + bv;
                }
            }
        }
    }
}

// ---------------------------------------------------------------------------
// Rotate — R20 chunk+tree structure, chain in PACKED f32 (v_pk_*_f32):
//   thread = (batch, row-pair rp/rp+16), f32x2 v[32]; one pk op covers both
//   rows -> chain VALU issue per row halves (R20 is VALU-bound: 74% busy).
//   pk asm verified on HW in R9 (passed); rev rule = neg moved to other fma.
//   Block 256 thr = 4 batches; wave w = chunk w (templates wave-uniform),
//   lane = batch*16 + rowpair. Tree = R15/R20 verified recipes, wave=batch
//   with pi/mi loops. GEMMs/prep identical to R20 (passing).
// LDS (f16 idx): PCM 8x1040 [0,8320) (cs f32 4x1000 overlays, dead after
// chains); EVEN 8x1040 [8320,16640) (R f32 4x1032 overlays after L1 reads);
// ODD [16640,24960). 49,920 B -> 3 blocks/CU.
// ---------------------------------------------------------------------------
struct IJTbl { unsigned char i[NANG]; unsigned char j[NANG]; };
constexpr IJTbl make_ij_tbl() {
    IJTbl t{};
    int k = 0;
    for (int i = 0; i < NROT - 1; ++i)
        for (int j = i + 1; j < NROT; ++j) { t.i[k] = (unsigned char)i; t.j[k] = (unsigned char)j; ++k; }
    return t;
}
constexpr IJTbl IJT = make_ij_tbl();

#define CS_STRIDE 1000   // f32 per-batch cs stride
#define SLOT_H    1040   // f16 per-slot stride (factors/PCM)
#define PCM_H     0      // f16 base: P slots (overlay cs)
#define EVEN_H    8320   // f16 base: even factors
#define ODD_H     16640  // f16 base: odd factors
#define RF32      4160   // f32 base: R (overlays EVEN)
#define R_STRIDE  1032   // f32 per-batch R stride

__device__ __forceinline__ f32x2 lo2(const f32x4 q) { return __builtin_shufflevector(q, q, 0, 1); }
__device__ __forceinline__ f32x2 hi2(const f32x4 q) { return __builtin_shufflevector(q, q, 2, 3); }

// One rotation K on the row-pair state; p = (c,s) packed. REV = column rule.
template<int K, bool REV>
__device__ __forceinline__ void rot1pk(const f32x2 p, f32x2 (&v)[NROT]) {
    constexpr int i = IJT.i[K], j = IJT.j[K];
    f32x2 t0, t1, ni, nj;
    asm("v_pk_mul_f32 %0, %1, %2 op_sel:[1,0] op_sel_hi:[1,1]"
        : "=v"(t0) : "v"(p), "v"(v[j]));          // t0 = s .* vj
    asm("v_pk_mul_f32 %0, %1, %2 op_sel:[1,0] op_sel_hi:[1,1]"
        : "=v"(t1) : "v"(p), "v"(v[i]));          // t1 = s .* vi
    if constexpr (!REV) {
        asm("v_pk_fma_f32 %0, %1, %2, %3 op_sel:[0,0,0] op_sel_hi:[0,1,1]"
            : "=v"(ni) : "v"(p), "v"(v[i]), "v"(t0));               // c*vi + s*vj
        asm("v_pk_fma_f32 %0, %1, %2, %3 op_sel:[0,0,0] op_sel_hi:[0,1,1] neg_lo:[0,0,1] neg_hi:[0,0,1]"
            : "=v"(nj) : "v"(p), "v"(v[j]), "v"(t1));               // c*vj - s*vi
    } else {
        asm("v_pk_fma_f32 %0, %1, %2, %3 op_sel:[0,0,0] op_sel_hi:[0,1,1] neg_lo:[0,0,1] neg_hi:[0,0,1]"
            : "=v"(ni) : "v"(p), "v"(v[i]), "v"(t0));               // c*vi - s*vj
        asm("v_pk_fma_f32 %0, %1, %2, %3 op_sel:[0,0,0] op_sel_hi:[0,1,1]"
            : "=v"(nj) : "v"(p), "v"(v[j]), "v"(t1));               // c*vj + s*vi
    }
    v[i] = ni; v[j] = nj;
}

template<int W, int T>
__device__ __forceinline__ void chain_step(const float* __restrict__ lcs,
                                           f32x2 (&v)[NROT]) {
    if constexpr ((W & 1) == 0) {
        constexpr int fi = 62 * W + T;                 // forward order
        const f32x4 q = *(const f32x4*)(lcs + fi * 4);
        rot1pk<2 * fi,     false>(lo2(q), v);
        rot1pk<2 * fi + 1, false>(hi2(q), v);
    } else {
        constexpr int fi = 62 * W + (61 - T);          // reverse order
        const f32x4 q = *(const f32x4*)(lcs + fi * 4);
        rot1pk<2 * fi + 1, true>(hi2(q), v);
        rot1pk<2 * fi,     true>(lo2(q), v);
    }
}

template<int W, size_t... Ts>
__device__ __forceinline__ void chain_runW(const float* __restrict__ lcs,
                                           f32x2 (&v)[NROT],
                                           std::index_sequence<Ts...>) {
    (chain_step<W, (int)Ts>(lcs, v), ...);
}

template<int W>
__device__ __forceinline__ void chain_and_store(const float* __restrict__ lcs,
                                                _Float16* __restrict__ lh,
                                                int b, int rp) {
    f32x2 v[NROT];
    #pragma unroll
    for (int c = 0; c < NROT; ++c) {
        f32x2 iv;
        iv[0] = (c == rp)      ? 1.f : 0.f;
        iv[1] = (c == rp + 16) ? 1.f : 0.f;
        v[c] = iv;
    }
    chain_runW<W>(lcs, v, std::make_index_sequence<62>{});

    constexpr int REG = ((W & 1) == 0) ? EVEN_H : ODD_H;
    const int base = REG + (b * 2 + (W >> 1)) * SLOT_H;
    #pragma unroll
    for (int kq = 0; kq < 4; ++kq) {
        half8 h0, h1;
        #pragma unroll
        for (int j = 0; j < 8; ++j) {
            h0[j] = (_Float16)v[kq * 8 + j][0];
            h1[j] = (_Float16)v[kq * 8 + j][1];
        }
        const int sw = (kq ^ (rp & 3)) << 3;          // (rp+16)&3 == rp&3
        *(half8*)&lh[base +  rp       * 32 + sw] = h0;
        *(half8*)&lh[base + (rp + 16) * 32 + sw] = h1;
    }
}

__global__ __launch_bounds__(256) void rotate_kernel(
    const float* __restrict__ theta, float* __restrict__ out)
{
    __shared__ float smem[12480];  // 49,920 B
    _Float16* lh = (_Float16*)smem;

    const int tid  = threadIdx.x;
    const int wid  = tid >> 6;             // 0..3 = chunk
    const int lane = tid & 63;
    const int lb   = lane >> 4;            // batch within block (0..3)
    const int rp   = lane & 15;            // row pair: rows rp, rp+16
    const int fr = lane & 15, fq = lane >> 4;
    const size_t b0 = (size_t)blockIdx.x * 4;

    // ---- stage: theta -> sincos -> (c,s) f32 pairs, per-batch padded ----
    #pragma unroll
    for (int it = 0; it < 2; ++it) {
        const int t = it * 256 + tid;
        if (t < 496) {
            const int b   = t / 124;
            const int idx = t - b * 124;
            const f32x4 th = *(const f32x4*)(theta + (b0 + b) * NANG + idx * 4);
            f32x4 p0, p1;
            float s, c;
            __sincosf(th[0], &s, &c); p0[0] = c; p0[1] = s;
            __sincosf(th[1], &s, &c); p0[2] = c; p0[3] = s;
            __sincosf(th[2], &s, &c); p1[0] = c; p1[1] = s;
            __sincosf(th[3], &s, &c); p1[2] = c; p1[3] = s;
            const int base = b * CS_STRIDE + idx * 8;
            *(f32x4*)&smem[base]     = p0;
            *(f32x4*)&smem[base + 4] = p1;
        }
    }
    __syncthreads();

    // ---- chunk chains: wave w = chunk w; lane -> (batch, row-pair) ----
    const float* lcs = smem + lb * CS_STRIDE;
    if      (wid == 0) chain_and_store<0>(lcs, lh, lb, rp);
    else if (wid == 1) chain_and_store<1>(lcs, lh, lb, rp);
    else if (wid == 2) chain_and_store<2>(lcs, lh, lb, rp);
    else               chain_and_store<3>(lcs, lh, lb, rp);
    __syncthreads();

    // ---- L1: wave = batch ba; loop pi: P_pi = C_{2pi} * C_{2pi+1} ----
    //  pi=0: mfma(C1^T, C0) = P0^T -> col-major store => PCM0 = P0 rows
    //  pi=1: mfma(C2, C3^T) = P1   -> col-major store => PCM1 = P1^T rows
    {
        const int ba = wid;
        const int swz = (fq ^ (fr & 3)) << 3;
        #pragma unroll
        for (int pi = 0; pi < 2; ++pi) {
            const int Eb = EVEN_H + (ba * 2 + pi) * SLOT_H;
            const int Ob = ODD_H  + (ba * 2 + pi) * SLOT_H;
            const int Asrc = (pi == 0) ? Ob : Eb;
            const int Bsrc = (pi == 0) ? Eb : Ob;
            half8 a[2], b[2];
            #pragma unroll
            for (int mi = 0; mi < 2; ++mi) {
                a[mi] = *(const half8*)&lh[Asrc + (mi * 16 + fr) * 32 + swz];
                b[mi] = *(const half8*)&lh[Bsrc + (mi * 16 + fr) * 32 + swz];
            }
            const int Pb = PCM_H + (ba * 2 + pi) * SLOT_H;
            #pragma unroll
            for (int mi = 0; mi < 2; ++mi)
                #pragma unroll
                for (int ni = 0; ni < 2; ++ni) {
                    const f32x4 d = __builtin_amdgcn_mfma_f32_16x16x32_f16(
                        a[mi], b[ni], (f32x4)(0.f), 0, 0, 0);
                    half4 hv;
                    #pragma unroll
                    for (int q = 0; q < 4; ++q) hv[q] = (_Float16)d[q];
                    const int col  = ni * 16 + fr;
                    const int rowb = (mi * 16 + fq * 4) ^ ((col & 3) << 3);
                    *(half4*)&lh[Pb + col * 32 + rowb] = hv;
                }
        }
    }
    __syncthreads();

    // ---- L2: wave = batch ba; mfma(PCM1, PCM0) = P1^T @ P0^T = R^T ----
    {
        const int ba = wid;
        const int Ab = PCM_H + (ba * 2 + 1) * SLOT_H;
        const int Bb = PCM_H + (ba * 2 + 0) * SLOT_H;
        const int swz = (fq ^ (fr & 3)) << 3;
        #pragma unroll
        for (int mi = 0; mi < 2; ++mi) {
            const half8 a = *(const half8*)&lh[Ab + (mi * 16 + fr) * 32 + swz];
            #pragma unroll
            for (int ni = 0; ni < 2; ++ni) {
                const half8 b = *(const half8*)&lh[Bb + (ni * 16 + fr) * 32 + swz];
                const f32x4 d = __builtin_amdgcn_mfma_f32_16x16x32_f16(
                    a, b, (f32x4)(0.f), 0, 0, 0);
                const int row  = ni * 16 + fr;
                const int colq = mi * 4 + fq;
                *(f32x4*)&smem[RF32 + ba * R_STRIDE + row * 32 + ((colq ^ (row & 7)) << 2)] = d;
            }
        }
    }
    __syncthreads();

    // ---- coalesced copy-out: 4 batches x 256 f4 ----
    #pragma unroll
    for (int s = 0; s < 4; ++s) {
        const int idx = s * 256 + tid;
        const int ba  = idx >> 8;
        const int f4i = idx & 255;
        const int row = f4i >> 3;
        const int cc  = f4i & 7;
        const f32x4 val =
            *(const f32x4*)&smem[RF32 + ba * R_STRIDE + row * 32 + ((cc ^ (row & 7)) << 2)];
        *(f32x4*)(out + (b0 + ba) * 1024 + (size_t)f4i * 4) = val;
    }
}

// ---------------------------------------------------------------------------
extern "C" void kernel_launch(void* const* d_in, const int* in_sizes, int n_in,
                              void* d_out, int out_size, void* d_ws, size_t ws_size,
                              hipStream_t stream)
{
    const float* x  = (const float*)d_in[0];   // [16384, 512]
    const float* W1 = (const float*)d_in[1];   // [1024, 512]
    const float* b1 = (const float*)d_in[2];   // [1024]
    const float* W2 = (const float*)d_in[3];   // [496, 1024]
    const float* b2 = (const float*)d_in[4];   // [496]
    float* out = (float*)d_out;                // [16384, 32, 32]

    _Float16* h16  = (_Float16*)d_out;
    _Float16* x16  = h16  + (size_t)BATCH * HIDDEN;
    _Float16* W116 = x16  + (size_t)BATCH * INPUT_DIM;
    _Float16* W216 = W116 + (size_t)HIDDEN * INPUT_DIM;
    float*    th   = (float*)d_ws;

    prep_f16<<<dim3((NX8 + NW18 + NW28) / 256), 256, 0, stream>>>(
        x, W1, W2, x16, W116, W216);

    gemm_nt_f16<0><<<dim3(8 * 128), 256, 0, stream>>>(
        x16, W116, b1, nullptr, h16, BATCH, INPUT_DIM, HIDDEN, 8);

    gemm_nt_f16<1><<<dim3(4 * 128), 256, 0, stream>>>(
        h16, W216, b2, th, nullptr, BATCH, HIDDEN, NANG, 4);

    rotate_kernel<<<dim3(BATCH / 4), 256, 0, stream>>>(th, out);
}

// Round 22
// 103.611 us; speedup vs baseline: 1.8160x; 1.0113x over previous
//
#include <hip/hip_runtime.h>
#include <math.h>
#include <utility>

#define BATCH 16384
#define INPUT_DIM 512
#define HIDDEN 1024
#define NROT 32
#define NANG 496   // 32*31/2

typedef _Float16 half8 __attribute__((ext_vector_type(8)));
typedef _Float16 half4 __attribute__((ext_vector_type(4)));
typedef float    f32x4 __attribute__((ext_vector_type(4)));
typedef float    f32x2 __attribute__((ext_vector_type(2)));

// ---------------------------------------------------------------------------
// Fused prep: x, W1, W2 -> f16 in one launch. W2 zero-padded 496 -> 512 rows.
// ---------------------------------------------------------------------------
#define NX8  (BATCH * INPUT_DIM / 8)
#define NW18 (HIDDEN * INPUT_DIM / 8)
#define NW28 (512 * HIDDEN / 8)

__global__ __launch_bounds__(256) void prep_f16(
    const float* __restrict__ x, const float* __restrict__ W1,
    const float* __restrict__ W2, _Float16* __restrict__ x16,
    _Float16* __restrict__ W116, _Float16* __restrict__ W216)
{
    const int i = blockIdx.x * 256 + threadIdx.x;
    const float* src; _Float16* dst; int j; bool zero = false;
    if (i < NX8)              { j = i;               src = x;  dst = x16;  }
    else if (i < NX8 + NW18)  { j = i - NX8;         src = W1; dst = W116; }
    else if (i < NX8 + NW18 + NW28) {
        j = i - NX8 - NW18;   src = W2; dst = W216;
        zero = (j * 8 >= NANG * HIDDEN);
    } else return;

    half8 h;
    if (zero) {
        #pragma unroll
        for (int q = 0; q < 8; ++q) h[q] = (_Float16)0.f;
    } else {
        const float4* s = (const float4*)src + (size_t)j * 2;
        const float4 a = s[0], b = s[1];
        h[0]=(_Float16)a.x; h[1]=(_Float16)a.y; h[2]=(_Float16)a.z; h[3]=(_Float16)a.w;
        h[4]=(_Float16)b.x; h[5]=(_Float16)b.y; h[6]=(_Float16)b.z; h[7]=(_Float16)b.w;
    }
    *(half8*)(dst + (size_t)j * 8) = h;
}

// ---------------------------------------------------------------------------
// f16 MFMA GEMM (NT), global_load_lds staging + XCD-local remap (passing)
// ---------------------------------------------------------------------------
__device__ __forceinline__ void gld16(const void* g, void* l) {
    __builtin_amdgcn_global_load_lds(
        (const __attribute__((address_space(1))) void*)g,
        (__attribute__((address_space(3))) void*)l, 16, 0, 0);
}

template<int EPI>
__global__ __launch_bounds__(256) void gemm_nt_f16(
    const _Float16* __restrict__ A, const _Float16* __restrict__ B,
    const float* __restrict__ bias, float* __restrict__ Cf,
    _Float16* __restrict__ Ch, int M, int K, int Nout, int GX)
{
    constexpr int BK = 32;
    __shared__ _Float16 sA[2][128 * BK];
    __shared__ _Float16 sB[2][128 * BK];

    const int g  = blockIdx.x;
    const int my = (g & 7) + (((g >> 3) / GX) << 3);
    const int mx = (g >> 3) % GX;
    const int m0 = my * 128;
    const int n0 = mx * 128;

    const int tid  = threadIdx.x;
    const int lane = tid & 63;
    const int wid  = tid >> 6;

    const int srow = lane >> 2;
    const int schk = (lane & 3) ^ (srow & 3);
    const _Float16* gA0 = A + (size_t)(m0 + wid * 32 + srow) * K + schk * 8;
    const _Float16* gA1 = gA0 + (size_t)16 * K;
    const _Float16* gB0 = B + (size_t)(n0 + wid * 32 + srow) * K + schk * 8;
    const _Float16* gB1 = gB0 + (size_t)16 * K;

    auto stage = [&](int kt, int buf) {
        const size_t ko = (size_t)kt * BK;
        gld16(gA0 + ko, &sA[buf][wid * 1024]);
        gld16(gA1 + ko, &sA[buf][wid * 1024 + 512]);
        gld16(gB0 + ko, &sB[buf][wid * 1024]);
        gld16(gB1 + ko, &sB[buf][wid * 1024 + 512]);
    };

    const int wr = wid >> 1, wc = wid & 1;
    const int fr = lane & 15, fq = lane >> 4;
    const int swR   = ((fq ^ (fr & 3)) << 3);
    const int aBase = (wr * 64 + fr) * BK + swR;
    const int bBase = (wc * 64 + fr) * BK + swR;

    f32x4 acc[4][4];
    #pragma unroll
    for (int i = 0; i < 4; ++i)
        #pragma unroll
        for (int j = 0; j < 4; ++j) acc[i][j] = (f32x4)(0.f);

    const int NT = K / BK;
    stage(0, 0);
    __syncthreads();
    int cur = 0;

    for (int kt = 0; kt < NT; ++kt) {
        if (kt + 1 < NT) stage(kt + 1, cur ^ 1);

        half8 a_[4], b_[4];
        #pragma unroll
        for (int f = 0; f < 4; ++f) {
            a_[f] = *(const half8*)&sA[cur][aBase + f * 16 * BK];
            b_[f] = *(const half8*)&sB[cur][bBase + f * 16 * BK];
        }
        #pragma unroll
        for (int fm = 0; fm < 4; ++fm)
            #pragma unroll
            for (int fn = 0; fn < 4; ++fn)
                acc[fm][fn] = __builtin_amdgcn_mfma_f32_16x16x32_f16(
                    a_[fm], b_[fn], acc[fm][fn], 0, 0, 0);

        __syncthreads();
        cur ^= 1;
    }

    if (EPI == 0) {
        #pragma unroll
        for (int fn = 0; fn < 4; ++fn) {
            const int col = n0 + wc * 64 + fn * 16 + fr;
            const float bv = bias[col];
            #pragma unroll
            for (int fm = 0; fm < 4; ++fm) {
                const int row0 = m0 + wr * 64 + fm * 16 + fq * 4;
                #pragma unroll
                for (int r = 0; r < 4; ++r)
                    Ch[(size_t)(row0 + r) * Nout + col] =
                        (_Float16)fmaxf(acc[fm][fn][r] + bv, 0.f);
            }
        }
    } else {
        #pragma unroll
        for (int fn = 0; fn < 4; ++fn) {
            const int col = n0 + wc * 64 + fn * 16 + fr;
            if (col < Nout) {
                const float bv = bias[col];
                #pragma unroll
                for (int fm = 0; fm < 4; ++fm) {
                    const int row0 = m0 + wr * 64 + fm * 16 + fq * 4;
                    #pragma unroll
                    for (int r = 0; r < 4; ++r)
                        Cf[(size_t)(row0 + r) * Nout + col] = acc[fm][fn][r] + bv;
                }
            }
        }
    }
}

// ---------------------------------------------------------------------------
// Rotate — R21 pk-chain + tree, SLOT-UNIFIED LDS (50 -> 33 KB => 4 blocks/CU):
//   one region of 16 slots x 2080 B, slot (b,w) = (b*4+w). Lifetimes are
//   sequential per slot:
//    (1) cs f32 for chunk w of batch b (248 f32 = 992 B) — read ONLY by wave
//        w (lockstep => all its reads precede its factor stores, no barrier);
//    (2) factor C_w / C_w^T f16 (2048 B), written by the same wave over cs;
//    (3) L1 reads factors -> barrier -> PCM over slots 0,1 of each batch;
//    (4) L2 reads PCM -> R f32 (4 KB) over slots 2,3. Copy-out from there.
//   Math/arithmetic byte-identical to R21 (passing, absmax 0.00390625).
// ---------------------------------------------------------------------------
struct IJTbl { unsigned char i[NANG]; unsigned char j[NANG]; };
constexpr IJTbl make_ij_tbl() {
    IJTbl t{};
    int k = 0;
    for (int i = 0; i < NROT - 1; ++i)
        for (int j = i + 1; j < NROT; ++j) { t.i[k] = (unsigned char)i; t.j[k] = (unsigned char)j; ++k; }
    return t;
}
constexpr IJTbl IJT = make_ij_tbl();

#define SLOT_H 1040   // f16 per slot (2080 B, 16B-aligned)
#define SLOT_F 520    // f32 per slot

__device__ __forceinline__ f32x2 lo2(const f32x4 q) { return __builtin_shufflevector(q, q, 0, 1); }
__device__ __forceinline__ f32x2 hi2(const f32x4 q) { return __builtin_shufflevector(q, q, 2, 3); }

// One rotation K on the row-pair state; p = (c,s) packed. REV = column rule.
template<int K, bool REV>
__device__ __forceinline__ void rot1pk(const f32x2 p, f32x2 (&v)[NROT]) {
    constexpr int i = IJT.i[K], j = IJT.j[K];
    f32x2 t0, t1, ni, nj;
    asm("v_pk_mul_f32 %0, %1, %2 op_sel:[1,0] op_sel_hi:[1,1]"
        : "=v"(t0) : "v"(p), "v"(v[j]));          // t0 = s .* vj
    asm("v_pk_mul_f32 %0, %1, %2 op_sel:[1,0] op_sel_hi:[1,1]"
        : "=v"(t1) : "v"(p), "v"(v[i]));          // t1 = s .* vi
    if constexpr (!REV) {
        asm("v_pk_fma_f32 %0, %1, %2, %3 op_sel:[0,0,0] op_sel_hi:[0,1,1]"
            : "=v"(ni) : "v"(p), "v"(v[i]), "v"(t0));
        asm("v_pk_fma_f32 %0, %1, %2, %3 op_sel:[0,0,0] op_sel_hi:[0,1,1] neg_lo:[0,0,1] neg_hi:[0,0,1]"
            : "=v"(nj) : "v"(p), "v"(v[j]), "v"(t1));
    } else {
        asm("v_pk_fma_f32 %0, %1, %2, %3 op_sel:[0,0,0] op_sel_hi:[0,1,1] neg_lo:[0,0,1] neg_hi:[0,0,1]"
            : "=v"(ni) : "v"(p), "v"(v[i]), "v"(t0));
        asm("v_pk_fma_f32 %0, %1, %2, %3 op_sel:[0,0,0] op_sel_hi:[0,1,1]"
            : "=v"(nj) : "v"(p), "v"(v[j]), "v"(t1));
    }
    v[i] = ni; v[j] = nj;
}

// chunk W, local cs group T (one f32x4 = 2 rotations); slot-local addressing.
template<int W, int T>
__device__ __forceinline__ void chain_step(const float* __restrict__ lcs,
                                           f32x2 (&v)[NROT]) {
    if constexpr ((W & 1) == 0) {
        constexpr int g = T;                          // forward order
        constexpr int K0 = 124 * W + 2 * g;
        const f32x4 q = *(const f32x4*)(lcs + g * 4);
        rot1pk<K0,     false>(lo2(q), v);
        rot1pk<K0 + 1, false>(hi2(q), v);
    } else {
        constexpr int g = 61 - T;                     // reverse order
        constexpr int K0 = 124 * W + 2 * g;
        const f32x4 q = *(const f32x4*)(lcs + g * 4);
        rot1pk<K0 + 1, true>(hi2(q), v);
        rot1pk<K0,     true>(lo2(q), v);
    }
}

template<int W, size_t... Ts>
__device__ __forceinline__ void chain_runW(const float* __restrict__ lcs,
                                           f32x2 (&v)[NROT],
                                           std::index_sequence<Ts...>) {
    (chain_step<W, (int)Ts>(lcs, v), ...);
}

template<int W>
__device__ __forceinline__ void chain_and_store(float* __restrict__ smemf,
                                                _Float16* __restrict__ lh,
                                                int b, int rp) {
    const float* lcs = smemf + (b * 4 + W) * SLOT_F;   // cs lives in own slot

    f32x2 v[NROT];
    #pragma unroll
    for (int c = 0; c < NROT; ++c) {
        f32x2 iv;
        iv[0] = (c == rp)      ? 1.f : 0.f;
        iv[1] = (c == rp + 16) ? 1.f : 0.f;
        v[c] = iv;
    }
    chain_runW<W>(lcs, v, std::make_index_sequence<62>{});

    // factor store overwrites the same slot (wave-lockstep: reads all done)
    const int base = (b * 4 + W) * SLOT_H;
    #pragma unroll
    for (int kq = 0; kq < 4; ++kq) {
        half8 h0, h1;
        #pragma unroll
        for (int j = 0; j < 8; ++j) {
            h0[j] = (_Float16)v[kq * 8 + j][0];
            h1[j] = (_Float16)v[kq * 8 + j][1];
        }
        const int sw = (kq ^ (rp & 3)) << 3;
        *(half8*)&lh[base +  rp       * 32 + sw] = h0;
        *(half8*)&lh[base + (rp + 16) * 32 + sw] = h1;
    }
}

__global__ __launch_bounds__(256) void rotate_kernel(
    const float* __restrict__ theta, float* __restrict__ out)
{
    __shared__ float smem[16 * SLOT_F];   // 33,280 B
    _Float16* lh = (_Float16*)smem;

    const int tid  = threadIdx.x;
    const int wid  = tid >> 6;             // 0..3 = chunk
    const int lane = tid & 63;
    const int lb   = lane >> 4;            // batch within block (0..3)
    const int rp   = lane & 15;            // row pair: rows rp, rp+16
    const int fr = lane & 15, fq = lane >> 4;
    const size_t b0 = (size_t)blockIdx.x * 4;

    // ---- stage: theta -> sincos -> (c,s) into slot (b, chunk) ----
    #pragma unroll
    for (int it = 0; it < 2; ++it) {
        const int t = it * 256 + tid;
        if (t < 496) {
            const int b    = t / 124;
            const int idx  = t - b * 124;      // theta f32x4 index 0..123
            const int w    = idx / 31;         // chunk
            const int lidx = idx - 31 * w;     // 0..30
            const f32x4 th = *(const f32x4*)(theta + (b0 + b) * NANG + idx * 4);
            f32x4 p0, p1;
            float s, c;
            __sincosf(th[0], &s, &c); p0[0] = c; p0[1] = s;
            __sincosf(th[1], &s, &c); p0[2] = c; p0[3] = s;
            __sincosf(th[2], &s, &c); p1[0] = c; p1[1] = s;
            __sincosf(th[3], &s, &c); p1[2] = c; p1[3] = s;
            const int base = (b * 4 + w) * SLOT_F + lidx * 8;
            *(f32x4*)&smem[base]     = p0;
            *(f32x4*)&smem[base + 4] = p1;
        }
    }
    __syncthreads();

    // ---- chunk chains: wave w = chunk w; lane -> (batch, row-pair) ----
    if      (wid == 0) chain_and_store<0>(smem, lh, lb, rp);
    else if (wid == 1) chain_and_store<1>(smem, lh, lb, rp);
    else if (wid == 2) chain_and_store<2>(smem, lh, lb, rp);
    else               chain_and_store<3>(smem, lh, lb, rp);
    __syncthreads();

    // ---- L1: wave = batch ba ----
    //  pi=0: mfma(C1^T, C0) = P0^T -> col-major store -> PCM0 = P0 rows
    //  pi=1: mfma(C2, C3^T) = P1   -> col-major store -> PCM1 = P1^T rows
    //  reads from slots (ba,0..3); after barrier, PCM0->slot(ba,0),
    //  PCM1->slot(ba,1).
    {
        const int ba = wid;
        const int swz = (fq ^ (fr & 3)) << 3;
        half8 a[2][2], b[2][2];
        #pragma unroll
        for (int pi = 0; pi < 2; ++pi) {
            const int Asl = (pi == 0) ? (ba * 4 + 1) : (ba * 4 + 2);
            const int Bsl = (pi == 0) ? (ba * 4 + 0) : (ba * 4 + 3);
            #pragma unroll
            for (int mi = 0; mi < 2; ++mi) {
                a[pi][mi] = *(const half8*)&lh[Asl * SLOT_H + (mi * 16 + fr) * 32 + swz];
                b[pi][mi] = *(const half8*)&lh[Bsl * SLOT_H + (mi * 16 + fr) * 32 + swz];
            }
        }
        f32x4 d[2][2][2];
        #pragma unroll
        for (int pi = 0; pi < 2; ++pi)
            #pragma unroll
            for (int mi = 0; mi < 2; ++mi)
                #pragma unroll
                for (int ni = 0; ni < 2; ++ni)
                    d[pi][mi][ni] = __builtin_amdgcn_mfma_f32_16x16x32_f16(
                        a[pi][mi], b[pi][ni], (f32x4)(0.f), 0, 0, 0);
        __syncthreads();   // all factor reads done before PCM overlays slots
        #pragma unroll
        for (int pi = 0; pi < 2; ++pi) {
            const int Pb = (ba * 4 + pi) * SLOT_H;
            #pragma unroll
            for (int mi = 0; mi < 2; ++mi)
                #pragma unroll
                for (int ni = 0; ni < 2; ++ni) {
                    half4 hv;
                    #pragma unroll
                    for (int q = 0; q < 4; ++q) hv[q] = (_Float16)d[pi][mi][ni][q];
                    const int col  = ni * 16 + fr;
                    const int rowb = (mi * 16 + fq * 4) ^ ((col & 3) << 3);
                    *(half4*)&lh[Pb + col * 32 + rowb] = hv;
                }
        }
    }
    __syncthreads();

    // ---- L2: wave = batch ba; mfma(PCM1, PCM0) = P1^T @ P0^T = R^T ----
    //  R f32 (4KB) overlays slots (ba,2),(ba,3).
    {
        const int ba = wid;
        const int Ab = (ba * 4 + 1) * SLOT_H;
        const int Bb = (ba * 4 + 0) * SLOT_H;
        const int Rb = (ba * 4 + 2) * SLOT_F;
        const int swz = (fq ^ (fr & 3)) << 3;
        #pragma unroll
        for (int mi = 0; mi < 2; ++mi) {
            const half8 a = *(const half8*)&lh[Ab + (mi * 16 + fr) * 32 + swz];
            #pragma unroll
            for (int ni = 0; ni < 2; ++ni) {
                const half8 b = *(const half8*)&lh[Bb + (ni * 16 + fr) * 32 + swz];
                const f32x4 d = __builtin_amdgcn_mfma_f32_16x16x32_f16(
                    a, b, (f32x4)(0.f), 0, 0, 0);
                const int row  = ni * 16 + fr;
                const int colq = mi * 4 + fq;
                *(f32x4*)&smem[Rb + row * 32 + ((colq ^ (row & 7)) << 2)] = d;
            }
        }
    }
    __syncthreads();

    // ---- coalesced copy-out: 4 batches x 256 f4 ----
    #pragma unroll
    for (int s = 0; s < 4; ++s) {
        const int idx = s * 256 + tid;
        const int ba  = idx >> 8;
        const int f4i = idx & 255;
        const int row = f4i >> 3;
        const int cc  = f4i & 7;
        const f32x4 val =
            *(const f32x4*)&smem[(ba * 4 + 2) * SLOT_F + row * 32 + ((cc ^ (row & 7)) << 2)];
        *(f32x4*)(out + (b0 + ba) * 1024 + (size_t)f4i * 4) = val;
    }
}

// ---------------------------------------------------------------------------
extern "C" void kernel_launch(void* const* d_in, const int* in_sizes, int n_in,
                              void* d_out, int out_size, void* d_ws, size_t ws_size,
                              hipStream_t stream)
{
    const float* x  = (const float*)d_in[0];   // [16384, 512]
    const float* W1 = (const float*)d_in[1];   // [1024, 512]
    const float* b1 = (const float*)d_in[2];   // [1024]
    const float* W2 = (const float*)d_in[3];   // [496, 1024]
    const float* b2 = (const float*)d_in[4];   // [496]
    float* out = (float*)d_out;                // [16384, 32, 32]

    _Float16* h16  = (_Float16*)d_out;
    _Float16* x16  = h16  + (size_t)BATCH * HIDDEN;
    _Float16* W116 = x16  + (size_t)BATCH * INPUT_DIM;
    _Float16* W216 = W116 + (size_t)HIDDEN * INPUT_DIM;
    float*    th   = (float*)d_ws;

    prep_f16<<<dim3((NX8 + NW18 + NW28) / 256), 256, 0, stream>>>(
        x, W1, W2, x16, W116, W216);

    gemm_nt_f16<0><<<dim3(8 * 128), 256, 0, stream>>>(
        x16, W116, b1, nullptr, h16, BATCH, INPUT_DIM, HIDDEN, 8);

    gemm_nt_f16<1><<<dim3(4 * 128), 256, 0, stream>>>(
        h16, W216, b2, th, nullptr, BATCH, HIDDEN, NANG, 4);

    rotate_kernel<<<dim3(BATCH / 4), 256, 0, stream>>>(th, out);
}